// Round 7
// baseline (98.805 us; speedup 1.0000x reference)
//
#include <hip/hip_runtime.h>

typedef unsigned int uint32;

namespace {
constexpr int CCH = 256;   // channels
constexpr int OUT = 7;     // output size
constexpr int S   = 14;    // OUT * SAMPLE_NUM
constexpr int NUM_ROIS = 1024;

constexpr int H0 = 200, W0 = 304;
constexpr int H1 = 100, W1 = 152;
constexpr int H2 = 50,  W2 = 76;
constexpr int H3 = 25,  W3 = 38;

constexpr int HW0 = H0 * W0;   // 60800
constexpr int HW1 = H1 * W1;   // 15200
constexpr int HW2 = H2 * W2;   // 3800
constexpr int HW3 = H3 * W3;   // 950

// transposed bf16 NHWC level sizes (in ushorts)
constexpr size_t US0 = (size_t)2 * HW0 * CCH;
constexpr size_t US1 = (size_t)2 * HW1 * CCH;
constexpr size_t US2 = (size_t)2 * HW2 * CCH;
constexpr size_t US3 = (size_t)2 * HW3 * CCH;

// hw-tiles of 64 per (batch, c-half): grid chunk = 4 * ceil(HW/64)
constexpr int TT0 = (HW0 + 63) / 64;   // 950 (exact)
constexpr int TT1 = (HW1 + 63) / 64;   // 238 (237 full + tail 32)
constexpr int TT2 = (HW2 + 63) / 64;   // 60  (59 full + tail 24)
constexpr int TT3 = (HW3 + 63) / 64;   // 15  (HW%4!=0 -> slow path)
constexpr int GG0 = 4 * TT0;           // 3800
constexpr int GG1 = 4 * TT1;           // 952
constexpr int GG2 = 4 * TT2;           // 240
constexpr int GG3 = 4 * TT3;           // 60

constexpr int RWORDS = 257;  // LDS region stride in words (1024B data + 4B gap)
}

__device__ __forceinline__ unsigned short f2bf(float f) {
    uint32 u = __float_as_uint(f);
    u += 0x7fffu + ((u >> 16) & 1u);          // round-to-nearest-even
    return (unsigned short)(u >> 16);
}
__device__ __forceinline__ float blo(uint32 u) { return __uint_as_float(u << 16); }
__device__ __forceinline__ float bhi(uint32 u) { return __uint_as_float(u & 0xffff0000u); }

// ---- NCHW fp32 -> NHWC bf16 transpose via global_load_lds ------------------
// Tile: 64 contiguous hw x 128 channels (one c-half). Phase A: 32 independent
// 1KB direct-to-LDS loads (4 waves x 8), no VGPR staging, one vmcnt(0) at the
// end. LDS: 32 regions of 4ch x 64hw fp32, region stride 1028B (gap makes
// phase-B strided reads 2-lanes/bank = free). Phase B: convert + pack, 64B
// contiguous NHWC store per thread.
__global__ __launch_bounds__(256) void transpose_gll(
    const float* __restrict__ f0, const float* __restrict__ f1,
    const float* __restrict__ f2, const float* __restrict__ f3,
    unsigned short* __restrict__ o0, unsigned short* __restrict__ o1,
    unsigned short* __restrict__ o2, unsigned short* __restrict__ o3)
{
    __shared__ uint32 lds[32 * RWORDS];
    int r = blockIdx.x;
    const float* in; unsigned short* op; int HW, TT;
    if (r < GG0)               {                  in = f0; op = o0; HW = HW0; TT = TT0; }
    else if (r < GG0+GG1)      { r -= GG0;        in = f1; op = o1; HW = HW1; TT = TT1; }
    else if (r < GG0+GG1+GG2)  { r -= GG0+GG1;    in = f2; op = o2; HW = HW2; TT = TT2; }
    else                       { r -= GG0+GG1+GG2; in = f3; op = o3; HW = HW3; TT = TT3; }
    const int b    = r / (2 * TT);
    const int rest = r - b * 2 * TT;
    const int half = rest / TT;
    const int tile = rest - half * TT;
    const int hw0  = tile * 64;

    const int t = threadIdx.x;
    const int l = t & 63;
    const int w = t >> 6;

    const float* src = in + (size_t)(b * CCH + half * 128) * HW;
    const bool fast = ((HW & 3) == 0) && (hw0 + 64 <= HW);

    if (fast) {
        #pragma unroll
        for (int j = 0; j < 8; ++j) {
            const int reg = w * 8 + j;                 // wave-uniform
            const int c   = 4 * reg + (l >> 4);        // per-lane channel
            const float* g = src + (size_t)c * HW + hw0 + (l & 15) * 4;
            __builtin_amdgcn_global_load_lds(
                (const __attribute__((address_space(1))) void*)g,
                (__attribute__((address_space(3))) void*)&lds[reg * RWORDS],
                16, 0, 0);
        }
        asm volatile("s_waitcnt vmcnt(0)" ::: "memory");
        __syncthreads();
    } else {
        #pragma unroll 1
        for (int j = 0; j < 8; ++j) {
            const int reg = w * 8 + j;
            const int c   = 4 * reg + (l >> 4);
            const int hwb = hw0 + (l & 15) * 4;
            #pragma unroll
            for (int i = 0; i < 4; ++i) {
                const int hw = hwb + i;
                float v = 0.0f;
                if (hw < HW) v = src[(size_t)c * HW + hw];
                lds[reg * RWORDS + l * 4 + i] = __float_as_uint(v);
            }
        }
        __syncthreads();
    }

    // ---- Phase B: fp32 LDS -> bf16 packed NHWC ----
    const int n    = min(64, HW - hw0);
    const int hw   = t >> 2;      // 0..63
    const int csub = t & 3;       // 32-channel quarter of the half
    if (hw < n) {
        uint32 outw[16];
        #pragma unroll
        for (int m = 0; m < 16; ++m) {
            const int c0 = csub * 32 + 2 * m;
            const int c1 = c0 + 1;
            const uint32 b0 = lds[(c0 >> 2) * RWORDS + (c0 & 3) * 64 + hw];
            const uint32 b1 = lds[(c1 >> 2) * RWORDS + (c1 & 3) * 64 + hw];
            outw[m] = (uint32)f2bf(__uint_as_float(b0))
                    | ((uint32)f2bf(__uint_as_float(b1)) << 16);
        }
        unsigned short* ob =
            op + ((size_t)b * HW + hw0 + hw) * CCH + half * 128 + csub * 32;
        *reinterpret_cast<uint4*>(ob +  0) = make_uint4(outw[0],  outw[1],  outw[2],  outw[3]);
        *reinterpret_cast<uint4*>(ob +  8) = make_uint4(outw[4],  outw[5],  outw[6],  outw[7]);
        *reinterpret_cast<uint4*>(ob + 16) = make_uint4(outw[8],  outw[9],  outw[10], outw[11]);
        *reinterpret_cast<uint4*>(ob + 24) = make_uint4(outw[12], outw[13], outw[14], outw[15]);
    }
}

// ---------------- gather from NHWC bf16 -------------------------------------
__global__ __launch_bounds__(256) void roi_gather_bf16(
    const unsigned short* __restrict__ w0, const unsigned short* __restrict__ w1,
    const unsigned short* __restrict__ w2, const unsigned short* __restrict__ w3,
    const float* __restrict__ rois, float* __restrict__ out)
{
    const int k = blockIdx.x;
    const int t = threadIdx.x;

    __shared__ float s_wlo[2][S];
    __shared__ float s_whi[2][S];
    __shared__ int   s_olo[2][S];   // offsets in uint2 units (y: W*64, x: 64)
    __shared__ int   s_ohi[2][S];
    __shared__ __align__(16) float s_out[25 * 260];

    const float rb  = rois[k*5+0];
    const float rx1 = rois[k*5+1];
    const float ry1 = rois[k*5+2];
    const float rx2 = rois[k*5+3];
    const float ry2 = rois[k*5+4];

    const float sc = sqrtf((rx2 - rx1 + 1.0f) * (ry2 - ry1 + 1.0f));
    int lvl = (int)floorf(log2f(sc * (1.0f/56.0f) + 1e-6f));
    lvl = lvl < 0 ? 0 : (lvl > 3 ? 3 : lvl);

    const unsigned short* fp; int H, W; float sp;
    if (lvl == 0)      { fp = w0; H = H0; W = W0; sp = 0.25f;    }
    else if (lvl == 1) { fp = w1; H = H1; W = W1; sp = 0.125f;   }
    else if (lvl == 2) { fp = w2; H = H2; W = W2; sp = 0.0625f;  }
    else               { fp = w3; H = H3; W = W3; sp = 0.03125f; }

    if (t < 2*S) {
        const int axis = (t >= S) ? 1 : 0;     // 0=y, 1=x
        const int i = axis ? (t - S) : t;
        const float lo = (axis ? rx1 : ry1) * sp;
        const float hi = (axis ? rx2 : ry2) * sp;
        const int dim  = axis ? W : H;
        const float len = fmaxf(hi - lo, 1.0f);
        const float bin = len * (1.0f / (float)S);
        const float v = lo + ((float)i + 0.5f) * bin;
        const bool valid = (v >= -1.0f) && (v <= (float)dim);
        float vc = fmaxf(v, 0.0f);
        int l = (int)floorf(vc);
        if (l >= dim - 1) { vc = (float)(dim - 1); l = dim - 1; }
        const int h = min(l + 1, dim - 1);
        const float frac = vc - (float)l;
        float wlo = 1.0f - frac;
        float whi = frac;
        if (!valid) { wlo = 0.0f; whi = 0.0f; }
        const int mul = axis ? 64 : W * 64;    // uint2 units
        s_wlo[axis][i] = wlo;
        s_whi[axis][i] = whi;
        s_olo[axis][i] = l * mul;
        s_ohi[axis][i] = h * mul;
    }
    __syncthreads();

    const int b = (int)rb;
    const int lane = t & 63;
    const int wv   = t >> 6;
    const uint2* __restrict__ base =
        reinterpret_cast<const uint2*>(fp) + (size_t)b * H * W * 64 + lane;
    float* __restrict__ ob = out + (size_t)k * CCH * (OUT * OUT);

    #pragma unroll
    for (int hf = 0; hf < 2; ++hf) {
        const int bb = hf ? 25 : 0;
        const int ne = hf ? 24 : 25;

        for (int bl = wv; bl < ne; bl += 4) {
            const int bin = bb + bl;
            const int oh = bin / 7;
            const int ow = bin - oh * 7;
            const int sy0 = oh * 2, sx0 = ow * 2;
            float a0 = 0.f, a1 = 0.f, a2 = 0.f, a3 = 0.f;
            #pragma unroll
            for (int dy = 0; dy < 2; ++dy) {
                const float hy = s_wlo[0][sy0 + dy];
                const float ly = s_whi[0][sy0 + dy];
                const int oyl = s_olo[0][sy0 + dy];
                const int oyh = s_ohi[0][sy0 + dy];
                #pragma unroll
                for (int dx = 0; dx < 2; ++dx) {
                    const float hx = s_wlo[1][sx0 + dx];
                    const float lx = s_whi[1][sx0 + dx];
                    const int oxl = s_olo[1][sx0 + dx];
                    const int oxh = s_ohi[1][sx0 + dx];
                    const uint2 qll = base[oyl + oxl];
                    const uint2 qlh = base[oyl + oxh];
                    const uint2 qhl = base[oyh + oxl];
                    const uint2 qhh = base[oyh + oxh];
                    const float wll = hy * hx, wlh = hy * lx;
                    const float whl = ly * hx, whh = ly * lx;
                    a0 += wll*blo(qll.x) + wlh*blo(qlh.x) + whl*blo(qhl.x) + whh*blo(qhh.x);
                    a1 += wll*bhi(qll.x) + wlh*bhi(qlh.x) + whl*bhi(qhl.x) + whh*bhi(qhh.x);
                    a2 += wll*blo(qll.y) + wlh*blo(qlh.y) + whl*blo(qhl.y) + whh*blo(qhh.y);
                    a3 += wll*bhi(qll.y) + wlh*bhi(qlh.y) + whl*bhi(qhl.y) + whh*bhi(qhh.y);
                }
            }
            float4 res = make_float4(a0*0.25f, a1*0.25f, a2*0.25f, a3*0.25f);
            *reinterpret_cast<float4*>(&s_out[bl * 260 + 4 * lane]) = res;
        }
        __syncthreads();

        #pragma unroll 1
        for (int j = 0; j < ne; ++j) {
            const int f = t + j * 256;
            const int c = f / ne;
            const int bl = f - c * ne;
            ob[c * (OUT*OUT) + bb + bl] = s_out[bl * 260 + c];
        }
        __syncthreads();
    }
}

// ---------------- fallback (direct NCHW fp32) if ws too small ---------------
__global__ __launch_bounds__(256) void roi_extract_direct(
    const float* __restrict__ f0, const float* __restrict__ f1,
    const float* __restrict__ f2, const float* __restrict__ f3,
    const float* __restrict__ rois, float* __restrict__ out)
{
    const int k = blockIdx.x;
    const int t = threadIdx.x;

    __shared__ float s_wlo[2][S];
    __shared__ float s_whi[2][S];
    __shared__ int   s_olo[2][S];
    __shared__ int   s_ohi[2][S];

    const float rb  = rois[k*5+0];
    const float rx1 = rois[k*5+1];
    const float ry1 = rois[k*5+2];
    const float rx2 = rois[k*5+3];
    const float ry2 = rois[k*5+4];

    const float sc = sqrtf((rx2 - rx1 + 1.0f) * (ry2 - ry1 + 1.0f));
    int lvl = (int)floorf(log2f(sc * (1.0f/56.0f) + 1e-6f));
    lvl = lvl < 0 ? 0 : (lvl > 3 ? 3 : lvl);

    const float* fp; int H, W; float sp;
    if (lvl == 0)      { fp = f0; H = H0; W = W0; sp = 0.25f;    }
    else if (lvl == 1) { fp = f1; H = H1; W = W1; sp = 0.125f;   }
    else if (lvl == 2) { fp = f2; H = H2; W = W2; sp = 0.0625f;  }
    else               { fp = f3; H = H3; W = W3; sp = 0.03125f; }

    if (t < 2*S) {
        const int axis = (t >= S) ? 1 : 0;
        const int i = axis ? (t - S) : t;
        const float lo = (axis ? rx1 : ry1) * sp;
        const float hi = (axis ? rx2 : ry2) * sp;
        const int dim  = axis ? W : H;
        const float len = fmaxf(hi - lo, 1.0f);
        const float bin = len * (1.0f / (float)S);
        const float v = lo + ((float)i + 0.5f) * bin;
        const bool valid = (v >= -1.0f) && (v <= (float)dim);
        float vc = fmaxf(v, 0.0f);
        int l = (int)floorf(vc);
        if (l >= dim - 1) { vc = (float)(dim - 1); l = dim - 1; }
        const int h = min(l + 1, dim - 1);
        const float frac = vc - (float)l;
        float wlo = 1.0f - frac;
        float whi = frac;
        if (!valid) { wlo = 0.0f; whi = 0.0f; }
        const int mul = axis ? 1 : W;
        s_wlo[axis][i] = wlo;
        s_whi[axis][i] = whi;
        s_olo[axis][i] = l * mul;
        s_ohi[axis][i] = h * mul;
    }
    __syncthreads();

    const int b = (int)rb;
    const float* __restrict__ base = fp + (size_t)(b * CCH + t) * (size_t)(H * W);
    float* __restrict__ obase = out + ((size_t)k * CCH + t) * (OUT * OUT);

    for (int oh = 0; oh < OUT; ++oh) {
        const int sy0 = oh * 2;
        const float hy0 = s_wlo[0][sy0],   ly0 = s_whi[0][sy0];
        const float hy1 = s_wlo[0][sy0+1], ly1 = s_whi[0][sy0+1];
        const int oyl0 = s_olo[0][sy0],   oyh0 = s_ohi[0][sy0];
        const int oyl1 = s_olo[0][sy0+1], oyh1 = s_ohi[0][sy0+1];
        #pragma unroll
        for (int ow = 0; ow < OUT; ++ow) {
            float acc = 0.0f;
            #pragma unroll
            for (int dx = 0; dx < 2; ++dx) {
                const int sx = ow * 2 + dx;
                const float hx = s_wlo[1][sx];
                const float lx = s_whi[1][sx];
                const int oxl = s_olo[1][sx];
                const int oxh = s_ohi[1][sx];
                acc += hy0 * (hx * base[oyl0 + oxl] + lx * base[oyl0 + oxh])
                     + ly0 * (hx * base[oyh0 + oxl] + lx * base[oyh0 + oxh])
                     + hy1 * (hx * base[oyl1 + oxl] + lx * base[oyl1 + oxh])
                     + ly1 * (hx * base[oyh1 + oxl] + lx * base[oyh1 + oxh]);
            }
            obase[oh * OUT + ow] = acc * 0.25f;
        }
    }
}

extern "C" void kernel_launch(void* const* d_in, const int* in_sizes, int n_in,
                              void* d_out, int out_size, void* d_ws, size_t ws_size,
                              hipStream_t stream) {
    const float* f0   = (const float*)d_in[0];
    const float* f1   = (const float*)d_in[1];
    const float* f2   = (const float*)d_in[2];
    const float* f3   = (const float*)d_in[3];
    const float* rois = (const float*)d_in[4];
    float* out = (float*)d_out;

    const size_t need_bytes = (US0 + US1 + US2 + US3) * sizeof(unsigned short);
    if (ws_size >= need_bytes) {
        unsigned short* ws0 = (unsigned short*)d_ws;
        unsigned short* ws1 = ws0 + US0;
        unsigned short* ws2 = ws1 + US1;
        unsigned short* ws3 = ws2 + US2;
        transpose_gll<<<GG0 + GG1 + GG2 + GG3, 256, 0, stream>>>(
            f0, f1, f2, f3, ws0, ws1, ws2, ws3);
        roi_gather_bf16<<<NUM_ROIS, 256, 0, stream>>>(ws0, ws1, ws2, ws3, rois, out);
    } else {
        roi_extract_direct<<<NUM_ROIS, 256, 0, stream>>>(f0, f1, f2, f3, rois, out);
    }
}

// Round 8
// 97.074 us; speedup vs baseline: 1.0178x; 1.0178x over previous
//
#include <hip/hip_runtime.h>

typedef unsigned int uint32;

namespace {
constexpr int CCH = 256;   // channels
constexpr int OUT = 7;     // output size
constexpr int S   = 14;    // OUT * SAMPLE_NUM
constexpr int NUM_ROIS = 1024;

constexpr int H0 = 200, W0 = 304;
constexpr int H1 = 100, W1 = 152;
constexpr int H2 = 50,  W2 = 76;
constexpr int H3 = 25,  W3 = 38;

constexpr int HW0 = H0 * W0;   // 60800
constexpr int HW1 = H1 * W1;   // 15200
constexpr int HW2 = H2 * W2;   // 3800
constexpr int HW3 = H3 * W3;   // 950

// transposed bf16 NHWC level sizes (in ushorts)
constexpr size_t US0 = (size_t)2 * HW0 * CCH;
constexpr size_t US1 = (size_t)2 * HW1 * CCH;
constexpr size_t US2 = (size_t)2 * HW2 * CCH;
constexpr size_t US3 = (size_t)2 * HW3 * CCH;

// hw-tiles of 64 per (batch, c-half): grid chunk = 4 * ceil(HW/64)
constexpr int TT0 = (HW0 + 63) / 64;   // 950 (exact)
constexpr int TT1 = (HW1 + 63) / 64;   // 238
constexpr int TT2 = (HW2 + 63) / 64;   // 60
constexpr int TT3 = (HW3 + 63) / 64;   // 15 (HW%4!=0 -> slow path)
constexpr int GG0 = 4 * TT0;           // 3800
constexpr int GG1 = 4 * TT1;           // 952
constexpr int GG2 = 4 * TT2;           // 240
constexpr int GG3 = 4 * TT3;           // 60

constexpr int LSTR = 65;   // LDS row stride in b32 words (64 c-pairs + 1 pad)
}

__device__ __forceinline__ unsigned short f2bf(float f) {
    uint32 u = __float_as_uint(f);
    u += 0x7fffu + ((u >> 16) & 1u);          // round-to-nearest-even
    return (unsigned short)(u >> 16);
}
__device__ __forceinline__ float blo(uint32 u) { return __uint_as_float(u << 16); }
__device__ __forceinline__ float bhi(uint32 u) { return __uint_as_float(u & 0xffff0000u); }

// ---- NCHW fp32 -> NHWC bf16 transpose, high-occupancy variant --------------
// Tile: 64 contiguous hw x 128 channels (one c-half). 16.6KB LDS (bf16 only)
// -> 8 blocks/CU. Per thread: 8 independent float4 loads (4ch x 8hw) staged in
// registers, convert+pack to b32 c-pairs, LDS stride 65 words (phase A ~2-way,
// phase B exactly 2-way = free). Phase B: 64B contiguous store per thread.
__global__ __launch_bounds__(256, 8) void transpose_hi(
    const float* __restrict__ f0, const float* __restrict__ f1,
    const float* __restrict__ f2, const float* __restrict__ f3,
    unsigned short* __restrict__ o0, unsigned short* __restrict__ o1,
    unsigned short* __restrict__ o2, unsigned short* __restrict__ o3)
{
    __shared__ uint32 lds[64 * LSTR];
    int r = blockIdx.x;
    const float* in; unsigned short* op; int HW, TT;
    if (r < GG0)               {                  in = f0; op = o0; HW = HW0; TT = TT0; }
    else if (r < GG0+GG1)      { r -= GG0;        in = f1; op = o1; HW = HW1; TT = TT1; }
    else if (r < GG0+GG1+GG2)  { r -= GG0+GG1;    in = f2; op = o2; HW = HW2; TT = TT2; }
    else                       { r -= GG0+GG1+GG2; in = f3; op = o3; HW = HW3; TT = TT3; }
    const int b    = r / (2 * TT);
    const int rest = r - b * 2 * TT;
    const int half = rest / TT;
    const int tile = rest - half * TT;
    const int hw0  = tile * 64;

    const int t  = threadIdx.x;
    const int hq = t & 7;      // hw octet: hw = hw0 + 8*hq .. +7
    const int cq = t >> 3;     // 0..31 -> channels 4cq..4cq+3 of the half

    const float* src = in + (size_t)(b * CCH + half * 128 + 4 * cq) * HW;
    const bool fast = ((HW & 3) == 0) && (hw0 + 64 <= HW);

    // ---- Phase A: 8 independent float4 loads into registers ----
    float4 v[8];   // [j*2+h]: channel j (0..3), hw-half h (0..1)
    if (fast) {
        const float* base = src + hw0 + 8 * hq;
        #pragma unroll
        for (int j = 0; j < 4; ++j) {
            #pragma unroll
            for (int h = 0; h < 2; ++h)
                v[j * 2 + h] = *reinterpret_cast<const float4*>(
                    base + (size_t)j * HW + 4 * h);
        }
    } else {
        #pragma unroll
        for (int j = 0; j < 4; ++j) {
            #pragma unroll
            for (int h = 0; h < 2; ++h) {
                float4 a = make_float4(0.f, 0.f, 0.f, 0.f);
                const int hwb = hw0 + 8 * hq + 4 * h;
                const float* p = src + (size_t)j * HW + hwb;
                if (hwb + 0 < HW) a.x = p[0];
                if (hwb + 1 < HW) a.y = p[1];
                if (hwb + 2 < HW) a.z = p[2];
                if (hwb + 3 < HW) a.w = p[3];
                v[j * 2 + h] = a;
            }
        }
    }

    // ---- convert + pack c-pairs, write LDS [hw][cpair] ----
    #pragma unroll
    for (int p = 0; p < 2; ++p) {          // cpair 2cq+p from channels 2p,2p+1
        #pragma unroll
        for (int h = 0; h < 2; ++h) {
            const float4 lo = v[(2 * p) * 2 + h];
            const float4 hi = v[(2 * p + 1) * 2 + h];
            const int row = 8 * hq + 4 * h;
            const int col = 2 * cq + p;
            lds[(row + 0) * LSTR + col] = (uint32)f2bf(lo.x) | ((uint32)f2bf(hi.x) << 16);
            lds[(row + 1) * LSTR + col] = (uint32)f2bf(lo.y) | ((uint32)f2bf(hi.y) << 16);
            lds[(row + 2) * LSTR + col] = (uint32)f2bf(lo.z) | ((uint32)f2bf(hi.z) << 16);
            lds[(row + 3) * LSTR + col] = (uint32)f2bf(lo.w) | ((uint32)f2bf(hi.w) << 16);
        }
    }
    __syncthreads();

    // ---- Phase B: 64B contiguous NHWC store per thread ----
    {
        const int row = t >> 2;        // hw row 0..63
        const int qd  = t & 3;         // 32-channel quarter of the half
        const int n   = min(64, HW - hw0);
        if (row < n) {
            uint32 wv[16];
            #pragma unroll
            for (int m = 0; m < 16; ++m)
                wv[m] = lds[row * LSTR + 16 * qd + m];
            unsigned short* ob =
                op + ((size_t)b * HW + hw0 + row) * CCH + half * 128 + qd * 32;
            *reinterpret_cast<uint4*>(ob +  0) = make_uint4(wv[0],  wv[1],  wv[2],  wv[3]);
            *reinterpret_cast<uint4*>(ob +  8) = make_uint4(wv[4],  wv[5],  wv[6],  wv[7]);
            *reinterpret_cast<uint4*>(ob + 16) = make_uint4(wv[8],  wv[9],  wv[10], wv[11]);
            *reinterpret_cast<uint4*>(ob + 24) = make_uint4(wv[12], wv[13], wv[14], wv[15]);
        }
    }
}

// ---------------- gather from NHWC bf16 -------------------------------------
__global__ __launch_bounds__(256) void roi_gather_bf16(
    const unsigned short* __restrict__ w0, const unsigned short* __restrict__ w1,
    const unsigned short* __restrict__ w2, const unsigned short* __restrict__ w3,
    const float* __restrict__ rois, float* __restrict__ out)
{
    const int k = blockIdx.x;
    const int t = threadIdx.x;

    __shared__ float s_wlo[2][S];
    __shared__ float s_whi[2][S];
    __shared__ int   s_olo[2][S];   // offsets in uint2 units (y: W*64, x: 64)
    __shared__ int   s_ohi[2][S];
    __shared__ __align__(16) float s_out[25 * 260];

    const float rb  = rois[k*5+0];
    const float rx1 = rois[k*5+1];
    const float ry1 = rois[k*5+2];
    const float rx2 = rois[k*5+3];
    const float ry2 = rois[k*5+4];

    const float sc = sqrtf((rx2 - rx1 + 1.0f) * (ry2 - ry1 + 1.0f));
    int lvl = (int)floorf(log2f(sc * (1.0f/56.0f) + 1e-6f));
    lvl = lvl < 0 ? 0 : (lvl > 3 ? 3 : lvl);

    const unsigned short* fp; int H, W; float sp;
    if (lvl == 0)      { fp = w0; H = H0; W = W0; sp = 0.25f;    }
    else if (lvl == 1) { fp = w1; H = H1; W = W1; sp = 0.125f;   }
    else if (lvl == 2) { fp = w2; H = H2; W = W2; sp = 0.0625f;  }
    else               { fp = w3; H = H3; W = W3; sp = 0.03125f; }

    if (t < 2*S) {
        const int axis = (t >= S) ? 1 : 0;     // 0=y, 1=x
        const int i = axis ? (t - S) : t;
        const float lo = (axis ? rx1 : ry1) * sp;
        const float hi = (axis ? rx2 : ry2) * sp;
        const int dim  = axis ? W : H;
        const float len = fmaxf(hi - lo, 1.0f);
        const float bin = len * (1.0f / (float)S);
        const float v = lo + ((float)i + 0.5f) * bin;
        const bool valid = (v >= -1.0f) && (v <= (float)dim);
        float vc = fmaxf(v, 0.0f);
        int l = (int)floorf(vc);
        if (l >= dim - 1) { vc = (float)(dim - 1); l = dim - 1; }
        const int h = min(l + 1, dim - 1);
        const float frac = vc - (float)l;
        float wlo = 1.0f - frac;
        float whi = frac;
        if (!valid) { wlo = 0.0f; whi = 0.0f; }
        const int mul = axis ? 64 : W * 64;    // uint2 units
        s_wlo[axis][i] = wlo;
        s_whi[axis][i] = whi;
        s_olo[axis][i] = l * mul;
        s_ohi[axis][i] = h * mul;
    }
    __syncthreads();

    const int b = (int)rb;
    const int lane = t & 63;
    const int wv   = t >> 6;
    const uint2* __restrict__ base =
        reinterpret_cast<const uint2*>(fp) + (size_t)b * H * W * 64 + lane;
    float* __restrict__ ob = out + (size_t)k * CCH * (OUT * OUT);

    #pragma unroll
    for (int hf = 0; hf < 2; ++hf) {
        const int bb = hf ? 25 : 0;
        const int ne = hf ? 24 : 25;

        for (int bl = wv; bl < ne; bl += 4) {
            const int bin = bb + bl;
            const int oh = bin / 7;
            const int ow = bin - oh * 7;
            const int sy0 = oh * 2, sx0 = ow * 2;
            float a0 = 0.f, a1 = 0.f, a2 = 0.f, a3 = 0.f;
            #pragma unroll
            for (int dy = 0; dy < 2; ++dy) {
                const float hy = s_wlo[0][sy0 + dy];
                const float ly = s_whi[0][sy0 + dy];
                const int oyl = s_olo[0][sy0 + dy];
                const int oyh = s_ohi[0][sy0 + dy];
                #pragma unroll
                for (int dx = 0; dx < 2; ++dx) {
                    const float hx = s_wlo[1][sx0 + dx];
                    const float lx = s_whi[1][sx0 + dx];
                    const int oxl = s_olo[1][sx0 + dx];
                    const int oxh = s_ohi[1][sx0 + dx];
                    const uint2 qll = base[oyl + oxl];
                    const uint2 qlh = base[oyl + oxh];
                    const uint2 qhl = base[oyh + oxl];
                    const uint2 qhh = base[oyh + oxh];
                    const float wll = hy * hx, wlh = hy * lx;
                    const float whl = ly * hx, whh = ly * lx;
                    a0 += wll*blo(qll.x) + wlh*blo(qlh.x) + whl*blo(qhl.x) + whh*blo(qhh.x);
                    a1 += wll*bhi(qll.x) + wlh*bhi(qlh.x) + whl*bhi(qhl.x) + whh*bhi(qhh.x);
                    a2 += wll*blo(qll.y) + wlh*blo(qlh.y) + whl*blo(qhl.y) + whh*blo(qhh.y);
                    a3 += wll*bhi(qll.y) + wlh*bhi(qlh.y) + whl*bhi(qhl.y) + whh*bhi(qhh.y);
                }
            }
            float4 res = make_float4(a0*0.25f, a1*0.25f, a2*0.25f, a3*0.25f);
            *reinterpret_cast<float4*>(&s_out[bl * 260 + 4 * lane]) = res;
        }
        __syncthreads();

        #pragma unroll 1
        for (int j = 0; j < ne; ++j) {
            const int f = t + j * 256;
            const int c = f / ne;
            const int bl = f - c * ne;
            ob[c * (OUT*OUT) + bb + bl] = s_out[bl * 260 + c];
        }
        __syncthreads();
    }
}

// ---------------- fallback (direct NCHW fp32) if ws too small ---------------
__global__ __launch_bounds__(256) void roi_extract_direct(
    const float* __restrict__ f0, const float* __restrict__ f1,
    const float* __restrict__ f2, const float* __restrict__ f3,
    const float* __restrict__ rois, float* __restrict__ out)
{
    const int k = blockIdx.x;
    const int t = threadIdx.x;

    __shared__ float s_wlo[2][S];
    __shared__ float s_whi[2][S];
    __shared__ int   s_olo[2][S];
    __shared__ int   s_ohi[2][S];

    const float rb  = rois[k*5+0];
    const float rx1 = rois[k*5+1];
    const float ry1 = rois[k*5+2];
    const float rx2 = rois[k*5+3];
    const float ry2 = rois[k*5+4];

    const float sc = sqrtf((rx2 - rx1 + 1.0f) * (ry2 - ry1 + 1.0f));
    int lvl = (int)floorf(log2f(sc * (1.0f/56.0f) + 1e-6f));
    lvl = lvl < 0 ? 0 : (lvl > 3 ? 3 : lvl);

    const float* fp; int H, W; float sp;
    if (lvl == 0)      { fp = f0; H = H0; W = W0; sp = 0.25f;    }
    else if (lvl == 1) { fp = f1; H = H1; W = W1; sp = 0.125f;   }
    else if (lvl == 2) { fp = f2; H = H2; W = W2; sp = 0.0625f;  }
    else               { fp = f3; H = H3; W = W3; sp = 0.03125f; }

    if (t < 2*S) {
        const int axis = (t >= S) ? 1 : 0;
        const int i = axis ? (t - S) : t;
        const float lo = (axis ? rx1 : ry1) * sp;
        const float hi = (axis ? rx2 : ry2) * sp;
        const int dim  = axis ? W : H;
        const float len = fmaxf(hi - lo, 1.0f);
        const float bin = len * (1.0f / (float)S);
        const float v = lo + ((float)i + 0.5f) * bin;
        const bool valid = (v >= -1.0f) && (v <= (float)dim);
        float vc = fmaxf(v, 0.0f);
        int l = (int)floorf(vc);
        if (l >= dim - 1) { vc = (float)(dim - 1); l = dim - 1; }
        const int h = min(l + 1, dim - 1);
        const float frac = vc - (float)l;
        float wlo = 1.0f - frac;
        float whi = frac;
        if (!valid) { wlo = 0.0f; whi = 0.0f; }
        const int mul = axis ? 1 : W;
        s_wlo[axis][i] = wlo;
        s_whi[axis][i] = whi;
        s_olo[axis][i] = l * mul;
        s_ohi[axis][i] = h * mul;
    }
    __syncthreads();

    const int b = (int)rb;
    const float* __restrict__ base = fp + (size_t)(b * CCH + t) * (size_t)(H * W);
    float* __restrict__ obase = out + ((size_t)k * CCH + t) * (OUT * OUT);

    for (int oh = 0; oh < OUT; ++oh) {
        const int sy0 = oh * 2;
        const float hy0 = s_wlo[0][sy0],   ly0 = s_whi[0][sy0];
        const float hy1 = s_wlo[0][sy0+1], ly1 = s_whi[0][sy0+1];
        const int oyl0 = s_olo[0][sy0],   oyh0 = s_ohi[0][sy0];
        const int oyl1 = s_olo[0][sy0+1], oyh1 = s_ohi[0][sy0+1];
        #pragma unroll
        for (int ow = 0; ow < OUT; ++ow) {
            float acc = 0.0f;
            #pragma unroll
            for (int dx = 0; dx < 2; ++dx) {
                const int sx = ow * 2 + dx;
                const float hx = s_wlo[1][sx];
                const float lx = s_whi[1][sx];
                const int oxl = s_olo[1][sx];
                const int oxh = s_ohi[1][sx];
                acc += hy0 * (hx * base[oyl0 + oxl] + lx * base[oyl0 + oxh])
                     + ly0 * (hx * base[oyh0 + oxl] + lx * base[oyh0 + oxh])
                     + hy1 * (hx * base[oyl1 + oxl] + lx * base[oyl1 + oxh])
                     + ly1 * (hx * base[oyh1 + oxl] + lx * base[oyh1 + oxh]);
            }
            obase[oh * OUT + ow] = acc * 0.25f;
        }
    }
}

extern "C" void kernel_launch(void* const* d_in, const int* in_sizes, int n_in,
                              void* d_out, int out_size, void* d_ws, size_t ws_size,
                              hipStream_t stream) {
    const float* f0   = (const float*)d_in[0];
    const float* f1   = (const float*)d_in[1];
    const float* f2   = (const float*)d_in[2];
    const float* f3   = (const float*)d_in[3];
    const float* rois = (const float*)d_in[4];
    float* out = (float*)d_out;

    const size_t need_bytes = (US0 + US1 + US2 + US3) * sizeof(unsigned short);
    if (ws_size >= need_bytes) {
        unsigned short* ws0 = (unsigned short*)d_ws;
        unsigned short* ws1 = ws0 + US0;
        unsigned short* ws2 = ws1 + US1;
        unsigned short* ws3 = ws2 + US2;
        transpose_hi<<<GG0 + GG1 + GG2 + GG3, 256, 0, stream>>>(
            f0, f1, f2, f3, ws0, ws1, ws2, ws3);
        roi_gather_bf16<<<NUM_ROIS, 256, 0, stream>>>(ws0, ws1, ws2, ws3, rois, out);
    } else {
        roi_extract_direct<<<NUM_ROIS, 256, 0, stream>>>(f0, f1, f2, f3, rois, out);
    }
}